// Round 5
// baseline (180.614 us; speedup 1.0000x reference)
//
#include <hip/hip_runtime.h>

typedef __attribute__((ext_vector_type(8))) short short8;
typedef __attribute__((ext_vector_type(4))) float f32x4;
typedef unsigned int u32;

#define NB 64
#define NC 3
#define NH 384
#define NW 384
#define HW (NH*NW)
#define NPATCH 576
#define NE 768
#define KDIM 768           // NC*16*16
#define MDIM (NB*NPATCH)   // 36864

#define BM 128
#define BN 128
#define NBLK_N (NE / BN)   // 6
#define NBLK_M (MDIM / BM) // 288
#define NWG (NBLK_M * NBLK_N)  // 1728
#define NKK 24             // K-steps of 32

#define TILE_B_BYTES (BN * 32 * 2)                 // 8192
#define WS_B_BYTES (NBLK_N * NKK * TILE_B_BYTES)   // 1,179,648

__device__ __forceinline__ unsigned short f2bf(float f) {
    unsigned int u = __builtin_bit_cast(unsigned int, f);
    u += 0x7fffu + ((u >> 16) & 1u);   // round-to-nearest-even
    return (unsigned short)(u >> 16);
}

// packed f32x2 -> bf16x2 (RNE), 1 VALU inst (no builtin on gfx950)
__device__ __forceinline__ u32 cvtpk(float lo, float hi) {
    u32 r;
    asm("v_cvt_pk_bf16_f32 %0, %1, %2" : "=v"(r) : "v"(lo), "v"(hi));
    return r;
}

// ---- pre-pass: proj_w fp32 [E][K] -> bf16 FRAGMENT-ORDER tile images ----
// Tile (bn,kk) = 8KB: slot s (0..511): g=s>>6, l=s&63 holds
// pw[e = bn*128 + g*16 + (l&15)][k = kk*32 + (l>>4)*8 .. +8] as 8 bf16.
// Wave wc reads fragment ni as 1KB contiguous: byte (wc*4+ni)*1024 + lane*16.
__global__ __launch_bounds__(256) void convert_w(
    const float* __restrict__ pw, unsigned char* __restrict__ wsb)
{
    int id = blockIdx.x * 256 + threadIdx.x;   // 6*24*512 = 73728 total
    int tile = id >> 9;            // bn*NKK + kk
    int s    = id & 511;
    int bn = tile / NKK;
    int kk = tile - bn * NKK;
    int g = s >> 6, l = s & 63;
    int e = bn * 128 + g * 16 + (l & 15);
    int k = kk * 32 + (l >> 4) * 8;

    const float4 f0 = *reinterpret_cast<const float4*>(pw + (size_t)e * KDIM + k);
    const float4 f1 = *reinterpret_cast<const float4*>(pw + (size_t)e * KDIM + k + 4);
    u32 a = (u32)f2bf(f0.x) | ((u32)f2bf(f0.y) << 16);
    u32 b = (u32)f2bf(f0.z) | ((u32)f2bf(f0.w) << 16);
    u32 c = (u32)f2bf(f1.x) | ((u32)f2bf(f1.y) << 16);
    u32 d = (u32)f2bf(f1.z) | ((u32)f2bf(f1.w) << 16);
    *reinterpret_cast<uint4*>(wsb + (size_t)tile * TILE_B_BYTES + s * 16) =
        make_uint4(a, b, c, d);
}

template <bool WSB>
__global__ __launch_bounds__(256, 2) void patch_embed_gemm(
    const float* __restrict__ x,
    const int* __restrict__ start_h,
    const int* __restrict__ start_w,
    const float* __restrict__ pw,
    const float* __restrict__ pb,
    const unsigned char* __restrict__ wsb,
    float* __restrict__ out)
{
    const int tid = threadIdx.x;
    // XCD-aware bijective swizzle (NWG%8==0): 6 bn-blocks sharing an A-panel
    // run consecutively on one XCD -> gather served from its L2.
    const int bid  = blockIdx.x;
    const int lbid = (bid & 7) * (NWG / 8) + (bid >> 3);
    const int bm = lbid / NBLK_N;
    const int bn = lbid - bm * NBLK_N;
    const int m0 = bm * BM;
    const int e0 = bn * BN;

    const int lane = tid & 63;
    const int wv   = tid >> 6;       // wave 0..3
    const int wr   = wv >> 1;        // 0..1 (64 m-rows)
    const int wc   = wv & 1;         // 0..1 (64 e-cols)
    const int lr   = lane & 15;
    const int lk   = lane >> 4;      // 0..3

    // Per-lane A-fragment base offsets (float units). Lane (lr,lk) of fragment
    // mi holds row m = m0+wr*64+mi*16+lr, k = lk*8..lk*8+7, i.e. 8 CONTIGUOUS
    // floats of one patch row: + (lk>>1)*NW selects h-subrow, + (lk&1)*8 the
    // w-half. Two dwordx4 loads per fragment, straight from x.
    int ab[4];
    #pragma unroll
    for (int mi = 0; mi < 4; ++mi) {
        int m = m0 + wr * 64 + mi * 16 + lr;
        int b = m / NPATCH;
        int n = m - b * NPATCH;
        ab[mi] = b * (NC * HW) + start_h[b * NPATCH + n] * NW
               + start_w[b * NPATCH + n] + (lk >> 1) * NW + (lk & 1) * 8;
    }

    const unsigned char* btiles = wsb + (size_t)bn * NKK * TILE_B_BYTES;
    const int bvoff = wc * 4096 + lane * 16;

    f32x4 acc[4][4] = {};

#define LOADA(KK, AR)                                                         \
    {                                                                         \
        const float* xk = x + ((KK) >> 3) * HW + ((KK) & 7) * 2 * NW;         \
        _Pragma("unroll")                                                     \
        for (int mi = 0; mi < 4; ++mi) {                                      \
            AR[mi][0] = *reinterpret_cast<const float4*>(xk + ab[mi]);        \
            AR[mi][1] = *reinterpret_cast<const float4*>(xk + ab[mi] + 4);    \
        }                                                                     \
    }

#define LOADB(KK, BR)                                                         \
    if (WSB) {                                                                \
        const unsigned char* bt = btiles + (size_t)(KK) * TILE_B_BYTES + bvoff;\
        _Pragma("unroll")                                                     \
        for (int ni = 0; ni < 4; ++ni)                                        \
            BR[ni] = *reinterpret_cast<const uint4*>(bt + ni * 1024);         \
    } else {                                                                  \
        _Pragma("unroll")                                                     \
        for (int ni = 0; ni < 4; ++ni) {                                      \
            int e = e0 + wc * 64 + ni * 16 + lr;                              \
            const float* bp = pw + (size_t)e * KDIM + (KK) * 32 + lk * 8;     \
            float4 g0 = *reinterpret_cast<const float4*>(bp);                 \
            float4 g1 = *reinterpret_cast<const float4*>(bp + 4);             \
            BR[ni] = make_uint4(cvtpk(g0.x, g0.y), cvtpk(g0.z, g0.w),         \
                                cvtpk(g1.x, g1.y), cvtpk(g1.z, g1.w));        \
        }                                                                     \
    }

#define STEP(AR, BR)                                                          \
    {                                                                         \
        _Pragma("unroll")                                                     \
        for (int mi = 0; mi < 4; ++mi) {                                      \
            short8 af = __builtin_bit_cast(short8, make_uint4(                \
                cvtpk(AR[mi][0].x, AR[mi][0].y),                              \
                cvtpk(AR[mi][0].z, AR[mi][0].w),                              \
                cvtpk(AR[mi][1].x, AR[mi][1].y),                              \
                cvtpk(AR[mi][1].z, AR[mi][1].w)));                            \
            _Pragma("unroll")                                                 \
            for (int ni = 0; ni < 4; ++ni)                                    \
                acc[mi][ni] = __builtin_amdgcn_mfma_f32_16x16x32_bf16(        \
                    af, __builtin_bit_cast(short8, BR[ni]),                   \
                    acc[mi][ni], 0, 0, 0);                                    \
        }                                                                     \
    }

    float4 a0[4][2], a1[4][2];
    uint4  b0[4],    b1[4];

    LOADA(0, a0)
    LOADB(0, b0)
    // unroll-by-2 register double-buffer; all indices static (rule #20).
    #pragma unroll 1
    for (int kk = 0; kk < NKK; kk += 2) {
        LOADA(kk + 1, a1)
        LOADB(kk + 1, b1)
        STEP(a0, b0)
        if (kk + 2 < NKK) {
            LOADA(kk + 2, a0)
            LOADB(kk + 2, b0)
        }
        STEP(a1, b1)
    }

#undef LOADA
#undef LOADB
#undef STEP

    // ---- epilogue: bias + store ----
    float biasv[4];
    #pragma unroll
    for (int ni = 0; ni < 4; ++ni)
        biasv[ni] = pb[e0 + wc * 64 + ni * 16 + lr];

    #pragma unroll
    for (int mi = 0; mi < 4; ++mi) {
        #pragma unroll
        for (int j = 0; j < 4; ++j) {
            int row = m0 + wr * 64 + mi * 16 + lk * 4 + j;
            float* orow = out + (size_t)row * NE + e0 + wc * 64 + lr;
            #pragma unroll
            for (int ni = 0; ni < 4; ++ni)
                orow[ni * 16] = acc[mi][ni][j] + biasv[ni];
        }
    }
}

extern "C" void kernel_launch(void* const* d_in, const int* in_sizes, int n_in,
                              void* d_out, int out_size, void* d_ws, size_t ws_size,
                              hipStream_t stream) {
    const float* x  = (const float*)d_in[0];
    const int* sh   = (const int*)d_in[1];
    const int* sw   = (const int*)d_in[2];
    const float* pw = (const float*)d_in[3];
    const float* pb = (const float*)d_in[4];
    float* out = (float*)d_out;

    if (ws_size >= (size_t)WS_B_BYTES) {
        unsigned char* wsb = (unsigned char*)d_ws;
        hipLaunchKernelGGL(convert_w, dim3(288), dim3(256), 0, stream, pw, wsb);
        hipLaunchKernelGGL(patch_embed_gemm<true>, dim3(NWG), dim3(256), 0, stream,
                           x, sh, sw, pw, pb, wsb, out);
    } else {
        hipLaunchKernelGGL(patch_embed_gemm<false>, dim3(NWG), dim3(256), 0, stream,
                           x, sh, sw, pw, pb, (const unsigned char*)nullptr, out);
    }
}

// Round 6
// 78.354 us; speedup vs baseline: 2.3051x; 2.3051x over previous
//
#include <hip/hip_runtime.h>

typedef __attribute__((ext_vector_type(8))) short short8;
typedef __attribute__((ext_vector_type(4))) float f32x4;
typedef unsigned int u32;

#define NB 64
#define NC 3
#define NH 384
#define NW 384
#define HW (NH*NW)
#define NPATCH 576
#define NE 768
#define KDIM 768           // NC*16*16
#define MDIM (NB*NPATCH)   // 36864

#define BM 128
#define BN 256
#define BK 64
#define NBLK_N (NE / BN)       // 3
#define NBLK_M (MDIM / BM)     // 288
#define NWG (NBLK_M * NBLK_N)  // 864
#define NKK (KDIM / BK)        // 12

#define TILE_B_BYTES (BN * BK * 2)                 // 32768
#define WS_B_BYTES (NBLK_N * NKK * TILE_B_BYTES)   // 1,179,648

#define GLOBAL_AS __attribute__((address_space(1)))
#define LDS_AS    __attribute__((address_space(3)))

__device__ __forceinline__ unsigned short f2bf(float f) {
    unsigned int u = __builtin_bit_cast(unsigned int, f);
    u += 0x7fffu + ((u >> 16) & 1u);   // round-to-nearest-even
    return (unsigned short)(u >> 16);
}

// packed f32x2 -> bf16x2 (RNE), 1 VALU inst (no builtin on gfx950)
__device__ __forceinline__ u32 cvtpk(float lo, float hi) {
    u32 r;
    asm("v_cvt_pk_bf16_f32 %0, %1, %2" : "=v"(r) : "v"(lo), "v"(hi));
    return r;
}

__device__ __forceinline__ void gload_lds16(const void* g, void* l) {
    __builtin_amdgcn_global_load_lds((const GLOBAL_AS u32*)g, (LDS_AS u32*)l, 16, 0, 0);
}

// ---- pre-pass: proj_w fp32 [E][K] -> bf16 tile images, XOR swizzle baked in ----
// Tile (bn,kk) = 32KB LDS image: row r = e&255 (128B = 64 bf16), 16B chunk ch
// stored at physical chunk ch^(r&7).
__global__ __launch_bounds__(256) void convert_w(
    const float* __restrict__ pw, unsigned char* __restrict__ wsb)
{
    int id = blockIdx.x * 256 + threadIdx.x;   // 768*96 = 73728 total
    int e  = id / 96;
    int ck = id - e * 96;          // 8-wide k-chunk 0..95
    int k0 = ck * 8;

    const float4 f0 = *reinterpret_cast<const float4*>(pw + (size_t)e * KDIM + k0);
    const float4 f1 = *reinterpret_cast<const float4*>(pw + (size_t)e * KDIM + k0 + 4);
    u32 a = (u32)f2bf(f0.x) | ((u32)f2bf(f0.y) << 16);
    u32 b = (u32)f2bf(f0.z) | ((u32)f2bf(f0.w) << 16);
    u32 c = (u32)f2bf(f1.x) | ((u32)f2bf(f1.y) << 16);
    u32 d = (u32)f2bf(f1.z) | ((u32)f2bf(f1.w) << 16);

    int bn = e >> 8;
    int r  = e & 255;
    int kk = k0 >> 6;
    int ch = (k0 & 63) >> 3;
    int off = (bn * NKK + kk) * TILE_B_BYTES + r * 128 + ((ch ^ (r & 7)) * 16);
    *reinterpret_cast<uint4*>(wsb + off) = make_uint4(a, b, c, d);
}

template <bool WSB>
__global__ __launch_bounds__(512, 4) void patch_embed_gemm(
    const float* __restrict__ x,
    const int* __restrict__ start_h,
    const int* __restrict__ start_w,
    const float* __restrict__ pw,
    const float* __restrict__ pb,
    const unsigned char* __restrict__ wsb,
    float* __restrict__ out)
{
    __shared__ __align__(16) unsigned short lA[2][BM * BK];  // 2 x 16 KB, swizzled
    __shared__ __align__(16) unsigned short lB[BN * BK];     // 32 KB, swizzled
    __shared__ int baseOff[BM];

    const int tid = threadIdx.x;
    // XCD-aware bijective swizzle (864 % 8 == 0): the 3 bn-blocks sharing an
    // A-panel run consecutively on one XCD -> gather re-reads hit its L2.
    const int bid  = blockIdx.x;
    const int lbid = (bid & 7) * (NWG / 8) + (bid >> 3);
    const int bm = lbid / NBLK_N;
    const int bn = lbid - bm * NBLK_N;
    const int m0 = bm * BM;
    const int e0 = bn * BN;

    if (tid < BM) {
        int m = m0 + tid;
        int b = m / NPATCH;
        int n = m - b * NPATCH;
        baseOff[tid] = b * (NC * HW) + start_h[b * NPATCH + n] * NW
                     + start_w[b * NPATCH + n];
    }

    const int lane = tid & 63;
    const int wv   = tid >> 6;       // wave 0..7
    const int wr   = wv >> 2;        // 0..1  (64 m-rows)
    const int wc   = wv & 3;         // 0..3  (64 e-cols)
    const int lr   = lane & 15;
    const int lk   = lane >> 4;      // 0..3

    // A staging decomposition: 16 threads/row, 32 rows/iter, 4 iters
    const int rt = tid >> 4;         // 0..31
    const int j0 = (tid & 15) * 4;   // float index within 64-wide k-slice
    const int chunk  = j0 >> 3;      // 16B chunk in row (0..7)
    const int within = j0 & 7;       // 0 or 4
    const int hsub   = j0 >> 4;      // 0..3
    const int wsub   = j0 & 15;      // 0,4,8,12

    __syncthreads();

    // per-thread gather bases for its 4 staged rows
    int ab[4];
    #pragma unroll
    for (int i = 0; i < 4; ++i)
        ab[i] = baseOff[i * 32 + rt] + hsub * NW + wsub;

    f32x4 acc[4][4] = {};
    float4 ar[4];

#define LOADA(KK)                                                             \
    {                                                                         \
        const int koff = ((KK) >> 2) * HW + ((KK) & 3) * 4 * NW;              \
        _Pragma("unroll")                                                     \
        for (int i = 0; i < 4; ++i)                                           \
            ar[i] = *reinterpret_cast<const float4*>(x + ab[i] + koff);       \
    }

#define WRITEA(BUF)                                                           \
    {                                                                         \
        _Pragma("unroll")                                                     \
        for (int i = 0; i < 4; ++i) {                                         \
            int r = i * 32 + rt;                                              \
            int off = r * BK + ((chunk ^ (r & 7)) * 8) + within;              \
            *reinterpret_cast<uint2*>(&lA[BUF][off]) =                        \
                make_uint2(cvtpk(ar[i].x, ar[i].y), cvtpk(ar[i].z, ar[i].w)); \
        }                                                                     \
    }

#define STAGEB(KK)                                                            \
    if (WSB) {                                                                \
        const unsigned char* src = wsb + (size_t)(bn * NKK + (KK)) * TILE_B_BYTES \
                                 + wv * 1024 + lane * 16;                     \
        unsigned char* dst = reinterpret_cast<unsigned char*>(lB) + wv * 1024;\
        _Pragma("unroll")                                                     \
        for (int i = 0; i < 4; ++i)                                           \
            gload_lds16(src + i * 8192, dst + i * 8192);                      \
    } else {                                                                  \
        _Pragma("unroll")                                                     \
        for (int i = 0; i < 8; ++i) {                                         \
            int r = i * 32 + rt;                                              \
            const float4 wf = *reinterpret_cast<const float4*>(               \
                pw + (size_t)(e0 + r) * KDIM + (KK) * BK + j0);               \
            int off = r * BK + ((chunk ^ (r & 7)) * 8) + within;              \
            *reinterpret_cast<uint2*>(&lB[off]) =                            \
                make_uint2(cvtpk(wf.x, wf.y), cvtpk(wf.z, wf.w));             \
        }                                                                     \
    }

#define COMPUTE(BUF)                                                          \
    {                                                                         \
        _Pragma("unroll")                                                     \
        for (int ks = 0; ks < 2; ++ks) {                                      \
            short8 af[4], bfr[4];                                             \
            _Pragma("unroll")                                                 \
            for (int mi = 0; mi < 4; ++mi) {                                  \
                int row = wr * 64 + mi * 16 + lr;                             \
                int off = row * BK + (((ks * 4 + lk) ^ (row & 7)) * 8);       \
                af[mi] = *reinterpret_cast<const short8*>(&lA[BUF][off]);     \
            }                                                                 \
            _Pragma("unroll")                                                 \
            for (int ni = 0; ni < 4; ++ni) {                                  \
                int row = wc * 64 + ni * 16 + lr;                             \
                int off = row * BK + (((ks * 4 + lk) ^ (row & 7)) * 8);       \
                bfr[ni] = *reinterpret_cast<const short8*>(&lB[off]);         \
            }                                                                 \
            _Pragma("unroll")                                                 \
            for (int mi = 0; mi < 4; ++mi)                                    \
                _Pragma("unroll")                                             \
                for (int ni = 0; ni < 4; ++ni)                                \
                    acc[mi][ni] = __builtin_amdgcn_mfma_f32_16x16x32_bf16(    \
                        af[mi], bfr[ni], acc[mi][ni], 0, 0, 0);               \
        }                                                                     \
    }

    // prologue: tile 0
    LOADA(0)
    WRITEA(0)           // compiler waits on ar's loads
    STAGEB(0)
    __syncthreads();    // drains gload_lds + ds_write

    for (int kk = 0; kk < NKK; ++kk) {
        const int buf = kk & 1;
        if (kk + 1 < NKK) LOADA(kk + 1)   // issue gather early: hides under compute
        COMPUTE(buf)
        __syncthreads();                  // all waves done reading lB / lA[buf]
        if (kk + 1 < NKK) {
            WRITEA(buf ^ 1)               // loads arrived during compute
            STAGEB(kk + 1)
        }
        __syncthreads();                  // tile k+1 ready
    }

#undef LOADA
#undef WRITEA
#undef STAGEB
#undef COMPUTE

    // ---- epilogue: bias + store ----
    float biasv[4];
    #pragma unroll
    for (int ni = 0; ni < 4; ++ni)
        biasv[ni] = pb[e0 + wc * 64 + ni * 16 + lr];

    #pragma unroll
    for (int mi = 0; mi < 4; ++mi) {
        #pragma unroll
        for (int j = 0; j < 4; ++j) {
            int row = m0 + wr * 64 + mi * 16 + lk * 4 + j;
            float* orow = out + (size_t)row * NE + e0 + wc * 64 + lr;
            #pragma unroll
            for (int ni = 0; ni < 4; ++ni)
                orow[ni * 16] = acc[mi][ni][j] + biasv[ni];
        }
    }
}

extern "C" void kernel_launch(void* const* d_in, const int* in_sizes, int n_in,
                              void* d_out, int out_size, void* d_ws, size_t ws_size,
                              hipStream_t stream) {
    const float* x  = (const float*)d_in[0];
    const int* sh   = (const int*)d_in[1];
    const int* sw   = (const int*)d_in[2];
    const float* pw = (const float*)d_in[3];
    const float* pb = (const float*)d_in[4];
    float* out = (float*)d_out;

    if (ws_size >= (size_t)WS_B_BYTES) {
        unsigned char* wsb = (unsigned char*)d_ws;
        hipLaunchKernelGGL(convert_w, dim3(288), dim3(256), 0, stream, pw, wsb);
        hipLaunchKernelGGL(patch_embed_gemm<true>, dim3(NWG), dim3(512), 0, stream,
                           x, sh, sw, pw, pb, wsb, out);
    } else {
        hipLaunchKernelGGL(patch_embed_gemm<false>, dim3(NWG), dim3(512), 0, stream,
                           x, sh, sw, pw, pb, (const unsigned char*)nullptr, out);
    }
}